// Round 1
// baseline (209.891 us; speedup 1.0000x reference)
//
#include <hip/hip_runtime.h>
#include <math.h>

// Problem shapes
// feature: (16, 32, 64, 64) f32
// img:     (16, 3, 512, 512) f32
// conv_w:  (16, 32, 16, 16) f32   (OIHW)
// conv_b:  (16,)
// lin_w:   (25, 144)
// lin_b:   (25,)
// out:     (16, 3, 512, 512) f32

#define B_  16
#define C_  3
#define H_  512
#define W_  512

// ---------------------------------------------------------------------------
// Stage 1: f[b, oc, i, j] = conv(patch(feature), conv_w, pad=1) + conv_b
// Output spatial 3x3, 16 out channels -> f is (16, 144) flattened oc*9+i*3+j.
// One wave (64 lanes) per output element; 2304 outputs total.
// ---------------------------------------------------------------------------
__global__ __launch_bounds__(256) void patch_conv_kernel(
    const float* __restrict__ feature,
    const float* __restrict__ conv_w,
    const float* __restrict__ conv_b,
    float* __restrict__ f_out)
{
    int wave = blockIdx.x * 4 + (threadIdx.x >> 6);
    int lane = threadIdx.x & 63;
    if (wave >= 2304) return;

    int b   = wave / 144;
    int rem = wave - b * 144;
    int oc  = rem / 9;
    int ij  = rem - oc * 9;
    int i   = ij / 3;
    int j   = ij - i * 3;

    const float* fb = feature + (size_t)b * 32 * 64 * 64;
    const float* wb = conv_w + (size_t)oc * 32 * 16 * 16;

    float acc = 0.0f;
    // 32 channels * 16*16 kernel = 8192 terms; lane-strided
    for (int t = lane; t < 8192; t += 64) {
        int ic = t >> 8;
        int r  = t & 255;
        int kh = r >> 4;
        int kw = r & 15;
        int y = i - 1 + kh;
        int x = j - 1 + kw;
        if ((unsigned)y < 16u && (unsigned)x < 16u) {
            acc += fb[ic * 4096 + y * 64 + x] * wb[t];
        }
    }
    // butterfly reduce across 64 lanes
    #pragma unroll
    for (int off = 32; off > 0; off >>= 1)
        acc += __shfl_xor(acc, off, 64);

    if (lane == 0)
        f_out[wave] = acc + conv_b[oc];
}

// ---------------------------------------------------------------------------
// Stage 2: kv[b,k] = sum_j gelu(f[b,j]) * lin_w[k,j] + lin_b[k]
// 16*25 = 400 outputs, 144-term dot each.
// ---------------------------------------------------------------------------
__global__ __launch_bounds__(256) void kv_kernel(
    const float* __restrict__ f_in,
    const float* __restrict__ lin_w,
    const float* __restrict__ lin_b,
    float* __restrict__ kv_out)
{
    int t = blockIdx.x * 256 + threadIdx.x;
    if (t >= B_ * 25) return;
    int b = t / 25;
    int k = t - b * 25;

    const float* fb = f_in + b * 144;
    const float* wk = lin_w + k * 144;
    float acc = lin_b[k];
    #pragma unroll 4
    for (int j = 0; j < 144; j++) {
        float x = fb[j];
        // exact gelu: x * 0.5 * (1 + erf(x/sqrt(2)))
        float g = 0.5f * x * (1.0f + erff(x * 0.70710678118654752f));
        acc += g * wk[j];
    }
    kv_out[t] = acc;
}

// ---------------------------------------------------------------------------
// Stage 3: depthwise 5x5 conv with reflect padding (pad=2).
// out[b,c,y,x] = sum_{dy,dx} kv[b, dy*5+dx] * img[b,c, refl(y-2+dy), refl(x-2+dx)]
// 64x64 output tile / block (256 thr), 68x68 input halo tile in LDS.
// Each thread: 4x4 outputs via float4 LDS reads, float4 stores.
// ---------------------------------------------------------------------------
#define TS   64          // output tile
#define ITS  68          // input tile (halo 2 each side)

__global__ __launch_bounds__(256) void depthwise_kernel(
    const float* __restrict__ img,
    const float* __restrict__ kv,
    float* __restrict__ out)
{
    __shared__ float tile_s[ITS * ITS];
    __shared__ float wsm[25];

    int bc   = blockIdx.y;          // 0..47  (b*3 + c)
    int b    = bc / C_;
    int tile = blockIdx.x;          // 0..63  (8x8 tiles)
    int ty0  = (tile >> 3) * TS;
    int tx0  = (tile & 7) * TS;

    int tid = threadIdx.x;
    if (tid < 25) wsm[tid] = kv[b * 25 + tid];

    const float* ip = img + (size_t)bc * H_ * W_;

    // load 68x68 halo tile with reflect mapping
    for (int i = tid; i < ITS * ITS; i += 256) {
        int ly = i / ITS;
        int lx = i - ly * ITS;
        int gy = ty0 + ly - 2;
        int gx = tx0 + lx - 2;
        gy = (gy < 0) ? -gy : ((gy >= H_) ? (2 * H_ - 2 - gy) : gy);
        gx = (gx < 0) ? -gx : ((gx >= W_) ? (2 * W_ - 2 - gx) : gx);
        tile_s[i] = ip[gy * W_ + gx];
    }
    __syncthreads();

    float w[25];
    #pragma unroll
    for (int i = 0; i < 25; i++) w[i] = wsm[i];

    int tx  = (tid & 15) * 4;   // 0..60
    int tyb = (tid >> 4) * 4;   // 0..60

    float* op = out + (size_t)bc * H_ * W_;

    #pragma unroll
    for (int r = 0; r < 4; r++) {
        int y = tyb + r;
        float acc0 = 0.f, acc1 = 0.f, acc2 = 0.f, acc3 = 0.f;
        #pragma unroll
        for (int dy = 0; dy < 5; dy++) {
            const float4* p = (const float4*)&tile_s[(y + dy) * ITS + tx];
            float4 va = p[0];
            float4 vb = p[1];
            float in0 = va.x, in1 = va.y, in2 = va.z, in3 = va.w;
            float in4 = vb.x, in5 = vb.y, in6 = vb.z, in7 = vb.w;
            float w0 = w[dy * 5 + 0];
            float w1 = w[dy * 5 + 1];
            float w2 = w[dy * 5 + 2];
            float w3 = w[dy * 5 + 3];
            float w4 = w[dy * 5 + 4];
            acc0 += w0 * in0 + w1 * in1 + w2 * in2 + w3 * in3 + w4 * in4;
            acc1 += w0 * in1 + w1 * in2 + w2 * in3 + w3 * in4 + w4 * in5;
            acc2 += w0 * in2 + w1 * in3 + w2 * in4 + w3 * in5 + w4 * in6;
            acc3 += w0 * in3 + w1 * in4 + w2 * in5 + w3 * in6 + w4 * in7;
        }
        float4 o;
        o.x = acc0; o.y = acc1; o.z = acc2; o.w = acc3;
        *(float4*)&op[(ty0 + y) * W_ + tx0 + tx] = o;
    }
}

extern "C" void kernel_launch(void* const* d_in, const int* in_sizes, int n_in,
                              void* d_out, int out_size, void* d_ws, size_t ws_size,
                              hipStream_t stream) {
    const float* feature = (const float*)d_in[0];
    const float* img     = (const float*)d_in[1];
    const float* conv_w  = (const float*)d_in[2];
    const float* conv_b  = (const float*)d_in[3];
    const float* lin_w   = (const float*)d_in[4];
    const float* lin_b   = (const float*)d_in[5];
    float* out = (float*)d_out;

    float* f_ws  = (float*)d_ws;            // 16*144 = 2304 floats
    float* kv_ws = f_ws + 2304;             // 16*25  = 400 floats

    // Stage 1: 2304 waves, 4 waves/block -> 576 blocks
    patch_conv_kernel<<<576, 256, 0, stream>>>(feature, conv_w, conv_b, f_ws);

    // Stage 2: 400 threads
    kv_kernel<<<2, 256, 0, stream>>>(f_ws, lin_w, lin_b, kv_ws);

    // Stage 3: 8x8 tiles per (b,c); 48 bc slices
    dim3 grid(64, B_ * C_);
    depthwise_kernel<<<grid, 256, 0, stream>>>(img, kv_ws, out);
}

// Round 2
// 142.885 us; speedup vs baseline: 1.4690x; 1.4690x over previous
//
#include <hip/hip_runtime.h>
#include <math.h>

// Problem shapes
// feature: (16, 32, 64, 64) f32
// img:     (16, 3, 512, 512) f32
// conv_w:  (16, 32, 16, 16) f32   (OIHW)
// conv_b:  (16,)
// lin_w:   (25, 144)
// lin_b:   (25,)
// out:     (16, 3, 512, 512) f32

#define B_  16
#define C_  3
#define H_  512
#define W_  512

// ---------------------------------------------------------------------------
// Stage 1: f[b, oc, i, j] = conv(patch(feature), conv_w, pad=1) + conv_b,
// then gelu (exact). Output g is (16, 144), flattened oc*9 + i*3 + j.
// One block per (b, oc): 256 blocks, 256 threads.
// Thread tid <-> spatial tap (kh,kw) = (tid>>4, tid&15) for ALL 32 in-chans;
// holds the 32 weights for its tap in registers, reads the staged patch from
// LDS at compile-time-constant offsets, masks boundary taps at the end.
// ---------------------------------------------------------------------------
__global__ __launch_bounds__(256) void patch_conv_kernel(
    const float* __restrict__ feature,
    const float* __restrict__ conv_w,
    const float* __restrict__ conv_b,
    float* __restrict__ g_out)
{
    __shared__ float patch_raw[17 + 8192 + 17]; // guard pads for +-17 offsets
    __shared__ float red[9][4];
    float* patch = patch_raw + 17;

    int blk = blockIdx.x;
    int b   = blk >> 4;
    int oc  = blk & 15;
    int tid = threadIdx.x;

    const float* fb = feature + (size_t)b * 32 * 4096;
    const float* wb = conv_w + (size_t)oc * 8192;

    if (tid < 17) { patch_raw[tid] = 0.f; patch_raw[17 + 8192 + tid] = 0.f; }

    // stage feature patch: (ic, kh, kw) -> patch[ic*256 + kh*16 + kw]
    for (int i = tid; i < 8192; i += 256) {
        int ic = i >> 8;
        int r  = i & 255;
        patch[i] = fb[ic * 4096 + (r >> 4) * 64 + (r & 15)];
    }

    // weights for this thread's tap across all 32 input channels (coalesced)
    float wreg[32];
    #pragma unroll
    for (int ic = 0; ic < 32; ic++) wreg[ic] = wb[ic * 256 + tid];

    __syncthreads();

    int kh = tid >> 4;
    int kw = tid & 15;

    float acc[9];
    #pragma unroll
    for (int k = 0; k < 9; k++) acc[k] = 0.f;

    #pragma unroll 4
    for (int ic = 0; ic < 32; ic++) {
        int base = ic * 256 + tid;
        float wv = wreg[ic];
        #pragma unroll
        for (int di = 0; di < 3; di++) {
            #pragma unroll
            for (int dj = 0; dj < 3; dj++) {
                acc[di * 3 + dj] += patch[base + (di - 1) * 16 + (dj - 1)] * wv;
            }
        }
    }

    // zero-pad conv: kill taps whose (y,x) = (kh+di-1, kw+dj-1) left [0,16)
    #pragma unroll
    for (int di = 0; di < 3; di++) {
        #pragma unroll
        for (int dj = 0; dj < 3; dj++) {
            bool ok = ((unsigned)(kh + di - 1) < 16u) &&
                      ((unsigned)(kw + dj - 1) < 16u);
            if (!ok) acc[di * 3 + dj] = 0.f;
        }
    }

    // reduce 256 partials per output: wave butterfly, then 4-wave combine
    #pragma unroll
    for (int k = 0; k < 9; k++) {
        float v = acc[k];
        #pragma unroll
        for (int off = 32; off > 0; off >>= 1)
            v += __shfl_xor(v, off, 64);
        acc[k] = v;
    }
    int wid  = tid >> 6;
    int lane = tid & 63;
    if (lane == 0) {
        #pragma unroll
        for (int k = 0; k < 9; k++) red[k][wid] = acc[k];
    }
    __syncthreads();
    if (tid < 9) {
        float s = red[tid][0] + red[tid][1] + red[tid][2] + red[tid][3];
        s += conv_b[oc];
        // exact gelu, fused here so stage 2 needs no erf
        float g = 0.5f * s * (1.0f + erff(s * 0.70710678118654752f));
        g_out[(b * 16 + oc) * 9 + tid] = g;
    }
}

// ---------------------------------------------------------------------------
// Stage 2: kv[b,k] = sum_j g[b,j] * lin_w[k,j] + lin_b[k]
// One block per b; lin_w (25x144 = 14.4 KB) + g row staged in LDS.
// ---------------------------------------------------------------------------
__global__ __launch_bounds__(256) void kv_kernel(
    const float* __restrict__ g_in,
    const float* __restrict__ lin_w,
    const float* __restrict__ lin_b,
    float* __restrict__ kv_out)
{
    __shared__ float wsh[25 * 144];
    __shared__ float gsh[144];
    int b   = blockIdx.x;
    int tid = threadIdx.x;

    for (int i = tid; i < 25 * 144; i += 256) wsh[i] = lin_w[i];
    if (tid < 144) gsh[tid] = g_in[b * 144 + tid];
    __syncthreads();

    if (tid < 25) {
        float acc = lin_b[tid];
        #pragma unroll 8
        for (int j = 0; j < 144; j++) acc += gsh[j] * wsh[tid * 144 + j];
        kv_out[b * 25 + tid] = acc;
    }
}

// ---------------------------------------------------------------------------
// Stage 3: depthwise 5x5 conv with reflect padding (pad=2).
// 64x64 output tile / block (256 thr), 68x68 input halo tile in LDS.
// Each thread: 4x4 outputs via float4 LDS reads, float4 stores.
// ---------------------------------------------------------------------------
#define TS   64          // output tile
#define ITS  68          // input tile (halo 2 each side)

__global__ __launch_bounds__(256) void depthwise_kernel(
    const float* __restrict__ img,
    const float* __restrict__ kv,
    float* __restrict__ out)
{
    __shared__ float tile_s[ITS * ITS];
    __shared__ float wsm[25];

    int bc   = blockIdx.y;          // 0..47  (b*3 + c)
    int b    = bc / C_;
    int tile = blockIdx.x;          // 0..63  (8x8 tiles)
    int ty0  = (tile >> 3) * TS;
    int tx0  = (tile & 7) * TS;

    int tid = threadIdx.x;
    if (tid < 25) wsm[tid] = kv[b * 25 + tid];

    const float* ip = img + (size_t)bc * H_ * W_;

    // load 68x68 halo tile with reflect mapping
    for (int i = tid; i < ITS * ITS; i += 256) {
        int ly = i / ITS;
        int lx = i - ly * ITS;
        int gy = ty0 + ly - 2;
        int gx = tx0 + lx - 2;
        gy = (gy < 0) ? -gy : ((gy >= H_) ? (2 * H_ - 2 - gy) : gy);
        gx = (gx < 0) ? -gx : ((gx >= W_) ? (2 * W_ - 2 - gx) : gx);
        tile_s[i] = ip[gy * W_ + gx];
    }
    __syncthreads();

    float w[25];
    #pragma unroll
    for (int i = 0; i < 25; i++) w[i] = wsm[i];

    int tx  = (tid & 15) * 4;   // 0..60
    int tyb = (tid >> 4) * 4;   // 0..60

    float* op = out + (size_t)bc * H_ * W_;

    #pragma unroll
    for (int r = 0; r < 4; r++) {
        int y = tyb + r;
        float acc0 = 0.f, acc1 = 0.f, acc2 = 0.f, acc3 = 0.f;
        #pragma unroll
        for (int dy = 0; dy < 5; dy++) {
            const float4* p = (const float4*)&tile_s[(y + dy) * ITS + tx];
            float4 va = p[0];
            float4 vb = p[1];
            float in0 = va.x, in1 = va.y, in2 = va.z, in3 = va.w;
            float in4 = vb.x, in5 = vb.y, in6 = vb.z, in7 = vb.w;
            float w0 = w[dy * 5 + 0];
            float w1 = w[dy * 5 + 1];
            float w2 = w[dy * 5 + 2];
            float w3 = w[dy * 5 + 3];
            float w4 = w[dy * 5 + 4];
            acc0 += w0 * in0 + w1 * in1 + w2 * in2 + w3 * in3 + w4 * in4;
            acc1 += w0 * in1 + w1 * in2 + w2 * in3 + w3 * in4 + w4 * in5;
            acc2 += w0 * in2 + w1 * in3 + w2 * in4 + w3 * in5 + w4 * in6;
            acc3 += w0 * in3 + w1 * in4 + w2 * in5 + w3 * in6 + w4 * in7;
        }
        float4 o;
        o.x = acc0; o.y = acc1; o.z = acc2; o.w = acc3;
        *(float4*)&op[(ty0 + y) * W_ + tx0 + tx] = o;
    }
}

extern "C" void kernel_launch(void* const* d_in, const int* in_sizes, int n_in,
                              void* d_out, int out_size, void* d_ws, size_t ws_size,
                              hipStream_t stream) {
    const float* feature = (const float*)d_in[0];
    const float* img     = (const float*)d_in[1];
    const float* conv_w  = (const float*)d_in[2];
    const float* conv_b  = (const float*)d_in[3];
    const float* lin_w   = (const float*)d_in[4];
    const float* lin_b   = (const float*)d_in[5];
    float* out = (float*)d_out;

    float* g_ws  = (float*)d_ws;            // 16*144 = 2304 floats (post-gelu)
    float* kv_ws = g_ws + 2304;             // 16*25  = 400 floats

    // Stage 1: one block per (b, oc)
    patch_conv_kernel<<<B_ * 16, 256, 0, stream>>>(feature, conv_w, conv_b, g_ws);

    // Stage 2: one block per b
    kv_kernel<<<B_, 256, 0, stream>>>(g_ws, lin_w, lin_b, kv_ws);

    // Stage 3: 8x8 tiles per (b,c); 48 bc slices
    dim3 grid(64, B_ * C_);
    depthwise_kernel<<<grid, 256, 0, stream>>>(img, kv_ws, out);
}

// Round 3
// 138.244 us; speedup vs baseline: 1.5183x; 1.0336x over previous
//
#include <hip/hip_runtime.h>
#include <math.h>

// Problem shapes
// feature: (16, 32, 64, 64) f32
// img:     (16, 3, 512, 512) f32
// conv_w:  (16, 32, 16, 16) f32   (OIHW)
// conv_b:  (16,)
// lin_w:   (25, 144)
// lin_b:   (25,)
// out:     (16, 3, 512, 512) f32

#define B_  16
#define C_  3
#define H_  512
#define W_  512

// ---------------------------------------------------------------------------
// Stage 1: f[b, oc, i, j] = conv(patch(feature), conv_w, pad=1) + conv_b,
// then gelu (exact). Output g is (16, 144), flattened oc*9 + i*3 + j.
// One block per (b, oc): 256 blocks, 256 threads.
// ---------------------------------------------------------------------------
__global__ __launch_bounds__(256) void patch_conv_kernel(
    const float* __restrict__ feature,
    const float* __restrict__ conv_w,
    const float* __restrict__ conv_b,
    float* __restrict__ g_out)
{
    __shared__ float patch_raw[17 + 8192 + 17]; // guard pads for +-17 offsets
    __shared__ float red[9][4];
    float* patch = patch_raw + 17;

    int blk = blockIdx.x;
    int b   = blk >> 4;
    int oc  = blk & 15;
    int tid = threadIdx.x;

    const float* fb = feature + (size_t)b * 32 * 4096;
    const float* wb = conv_w + (size_t)oc * 8192;

    if (tid < 17) { patch_raw[tid] = 0.f; patch_raw[17 + 8192 + tid] = 0.f; }

    // stage feature patch: (ic, kh, kw) -> patch[ic*256 + kh*16 + kw]
    for (int i = tid; i < 8192; i += 256) {
        int ic = i >> 8;
        int r  = i & 255;
        patch[i] = fb[ic * 4096 + (r >> 4) * 64 + (r & 15)];
    }

    // weights for this thread's tap across all 32 input channels (coalesced)
    float wreg[32];
    #pragma unroll
    for (int ic = 0; ic < 32; ic++) wreg[ic] = wb[ic * 256 + tid];

    __syncthreads();

    int kh = tid >> 4;
    int kw = tid & 15;

    float acc[9];
    #pragma unroll
    for (int k = 0; k < 9; k++) acc[k] = 0.f;

    #pragma unroll 4
    for (int ic = 0; ic < 32; ic++) {
        int base = ic * 256 + tid;
        float wv = wreg[ic];
        #pragma unroll
        for (int di = 0; di < 3; di++) {
            #pragma unroll
            for (int dj = 0; dj < 3; dj++) {
                acc[di * 3 + dj] += patch[base + (di - 1) * 16 + (dj - 1)] * wv;
            }
        }
    }

    // zero-pad conv: kill taps whose (y,x) = (kh+di-1, kw+dj-1) left [0,16)
    #pragma unroll
    for (int di = 0; di < 3; di++) {
        #pragma unroll
        for (int dj = 0; dj < 3; dj++) {
            bool ok = ((unsigned)(kh + di - 1) < 16u) &&
                      ((unsigned)(kw + dj - 1) < 16u);
            if (!ok) acc[di * 3 + dj] = 0.f;
        }
    }

    // reduce 256 partials per output: wave butterfly, then 4-wave combine
    #pragma unroll
    for (int k = 0; k < 9; k++) {
        float v = acc[k];
        #pragma unroll
        for (int off = 32; off > 0; off >>= 1)
            v += __shfl_xor(v, off, 64);
        acc[k] = v;
    }
    int wid  = tid >> 6;
    int lane = tid & 63;
    if (lane == 0) {
        #pragma unroll
        for (int k = 0; k < 9; k++) red[k][wid] = acc[k];
    }
    __syncthreads();
    if (tid < 9) {
        float s = red[tid][0] + red[tid][1] + red[tid][2] + red[tid][3];
        s += conv_b[oc];
        float g = 0.5f * s * (1.0f + erff(s * 0.70710678118654752f));
        g_out[(b * 16 + oc) * 9 + tid] = g;
    }
}

// ---------------------------------------------------------------------------
// Stage 2: kv[b,k] = sum_j g[b,j] * lin_w[k,j] + lin_b[k]
// ---------------------------------------------------------------------------
__global__ __launch_bounds__(256) void kv_kernel(
    const float* __restrict__ g_in,
    const float* __restrict__ lin_w,
    const float* __restrict__ lin_b,
    float* __restrict__ kv_out)
{
    __shared__ float wsh[25 * 144];
    __shared__ float gsh[144];
    int b   = blockIdx.x;
    int tid = threadIdx.x;

    for (int i = tid; i < 25 * 144; i += 256) wsh[i] = lin_w[i];
    if (tid < 144) gsh[tid] = g_in[b * 144 + tid];
    __syncthreads();

    if (tid < 25) {
        float acc = lin_b[tid];
        #pragma unroll 8
        for (int j = 0; j < 144; j++) acc += gsh[j] * wsh[tid * 144 + j];
        kv_out[b * 25 + tid] = acc;
    }
}

// ---------------------------------------------------------------------------
// Stage 3: depthwise 5x5 conv, reflect pad=2.
// 64x64 output tile / block (256 thr), 68x68 halo tile in LDS.
// Register row-streaming: each thread computes a 4x4 patch, loading each of
// its 8 input rows from LDS exactly ONCE (2 x ds_read_b128), accumulating
// into all (orow, dy = r - orow) pairs as rows stream by. 16 b128/thread
// instead of 40 -> 2.5x less LDS pipe pressure.
// ---------------------------------------------------------------------------
#define TS   64          // output tile
#define ITS  68          // input tile (halo 2 each side)

__device__ __forceinline__ int reflect_idx(int v, int n) {
    v = (v < 0) ? -v : v;
    v = (v >= n) ? (2 * n - 2 - v) : v;
    return v;
}

__global__ __launch_bounds__(256) void depthwise_kernel(
    const float* __restrict__ img,
    const float* __restrict__ kv,
    float* __restrict__ out)
{
    __shared__ float tile_s[ITS * ITS];
    __shared__ float wsm[25];

    int bc   = blockIdx.y;          // 0..47  (b*3 + c)
    int b    = bc / C_;
    int tile = blockIdx.x;          // 0..63  (8x8 tiles)
    int ty0  = (tile >> 3) * TS;
    int tx0  = (tile & 7) * TS;

    int tid = threadIdx.x;
    if (tid < 25) wsm[tid] = kv[b * 25 + tid];

    const float* ip = img + (size_t)bc * H_ * W_;

    // --- stage 68x68 halo tile, float2-vectorized (34 chunks/row) ---
    bool xedge = (tx0 == 0) || (tx0 == W_ - TS);
    for (int i = tid; i < ITS * 34; i += 256) {
        int ly = i / 34;
        int c  = i - ly * 34;
        int gy = reflect_idx(ty0 + ly - 2, H_);
        int gx = tx0 + 2 * c - 2;
        const float* rowp = ip + gy * W_;
        float2 v;
        if (!xedge || (unsigned)gx < (unsigned)(W_ - 1)) {
            v = *(const float2*)&rowp[gx];         // gx even -> 8B aligned
        } else {
            v.x = rowp[reflect_idx(gx, W_)];
            v.y = rowp[reflect_idx(gx + 1, W_)];
        }
        *(float2*)&tile_s[ly * ITS + 2 * c] = v;   // ITS even -> aligned
    }
    __syncthreads();

    float w[25];
    #pragma unroll
    for (int i = 0; i < 25; i++) w[i] = wsm[i];

    int tx = (tid & 15) * 4;   // 0..60
    int ty = (tid >> 4) * 4;   // 0..60

    float acc[4][4];
    #pragma unroll
    for (int i = 0; i < 4; i++)
        #pragma unroll
        for (int j = 0; j < 4; j++) acc[i][j] = 0.f;

    // stream 8 input rows; each loaded exactly once
    #pragma unroll
    for (int r = 0; r < 8; r++) {
        const float* rowp = &tile_s[(ty + r) * ITS + tx];
        float4 a = *(const float4*)rowp;
        float4 bb = *(const float4*)(rowp + 4);
        float x0 = a.x, x1 = a.y, x2 = a.z, x3 = a.w;
        float x4 = bb.x, x5 = bb.y, x6 = bb.z, x7 = bb.w;
        float x[8] = {x0, x1, x2, x3, x4, x5, x6, x7};
        #pragma unroll
        for (int orow = 0; orow < 4; orow++) {
            int dy = r - orow;
            if (dy >= 0 && dy < 5) {          // compile-time after unroll
                #pragma unroll
                for (int dx = 0; dx < 5; dx++) {
                    float wv = w[dy * 5 + dx];
                    #pragma unroll
                    for (int oc = 0; oc < 4; oc++)
                        acc[orow][oc] += wv * x[oc + dx];
                }
            }
        }
    }

    float* op = out + (size_t)bc * H_ * W_;
    #pragma unroll
    for (int orow = 0; orow < 4; orow++) {
        float4 o;
        o.x = acc[orow][0]; o.y = acc[orow][1];
        o.z = acc[orow][2]; o.w = acc[orow][3];
        *(float4*)&op[(ty0 + ty + orow) * W_ + tx0 + tx] = o;
    }
}

extern "C" void kernel_launch(void* const* d_in, const int* in_sizes, int n_in,
                              void* d_out, int out_size, void* d_ws, size_t ws_size,
                              hipStream_t stream) {
    const float* feature = (const float*)d_in[0];
    const float* img     = (const float*)d_in[1];
    const float* conv_w  = (const float*)d_in[2];
    const float* conv_b  = (const float*)d_in[3];
    const float* lin_w   = (const float*)d_in[4];
    const float* lin_b   = (const float*)d_in[5];
    float* out = (float*)d_out;

    float* g_ws  = (float*)d_ws;            // 16*144 floats (post-gelu)
    float* kv_ws = g_ws + 2304;             // 16*25 floats

    patch_conv_kernel<<<B_ * 16, 256, 0, stream>>>(feature, conv_w, conv_b, g_ws);
    kv_kernel<<<B_, 256, 0, stream>>>(g_ws, lin_w, lin_b, kv_ws);

    dim3 grid(64, B_ * C_);
    depthwise_kernel<<<grid, 256, 0, stream>>>(img, kv_ws, out);
}

// Round 4
// 136.607 us; speedup vs baseline: 1.5365x; 1.0120x over previous
//
#include <hip/hip_runtime.h>
#include <math.h>

// Problem shapes
// feature: (16, 32, 64, 64) f32
// img:     (16, 3, 512, 512) f32
// conv_w:  (16, 32, 16, 16) f32   (OIHW)
// conv_b:  (16,)
// lin_w:   (25, 144)
// lin_b:   (25,)
// out:     (16, 3, 512, 512) f32

#define B_  16
#define C_  3
#define H_  512
#define W_  512

// ---------------------------------------------------------------------------
// Stage 1: 16x16 conv (pad=1) on the 16x16 feature patch + bias + exact gelu.
// One block per (b, oc); thread <-> spatial tap for all 32 input channels.
// ---------------------------------------------------------------------------
__global__ __launch_bounds__(256) void patch_conv_kernel(
    const float* __restrict__ feature,
    const float* __restrict__ conv_w,
    const float* __restrict__ conv_b,
    float* __restrict__ g_out)
{
    __shared__ float patch_raw[17 + 8192 + 17]; // guard pads for +-17 offsets
    __shared__ float red[9][4];
    float* patch = patch_raw + 17;

    int blk = blockIdx.x;
    int b   = blk >> 4;
    int oc  = blk & 15;
    int tid = threadIdx.x;

    const float* fb = feature + (size_t)b * 32 * 4096;
    const float* wb = conv_w + (size_t)oc * 8192;

    if (tid < 17) { patch_raw[tid] = 0.f; patch_raw[17 + 8192 + tid] = 0.f; }

    for (int i = tid; i < 8192; i += 256) {
        int ic = i >> 8;
        int r  = i & 255;
        patch[i] = fb[ic * 4096 + (r >> 4) * 64 + (r & 15)];
    }

    float wreg[32];
    #pragma unroll
    for (int ic = 0; ic < 32; ic++) wreg[ic] = wb[ic * 256 + tid];

    __syncthreads();

    int kh = tid >> 4;
    int kw = tid & 15;

    float acc[9];
    #pragma unroll
    for (int k = 0; k < 9; k++) acc[k] = 0.f;

    #pragma unroll 4
    for (int ic = 0; ic < 32; ic++) {
        int base = ic * 256 + tid;
        float wv = wreg[ic];
        #pragma unroll
        for (int di = 0; di < 3; di++) {
            #pragma unroll
            for (int dj = 0; dj < 3; dj++) {
                acc[di * 3 + dj] += patch[base + (di - 1) * 16 + (dj - 1)] * wv;
            }
        }
    }

    #pragma unroll
    for (int di = 0; di < 3; di++) {
        #pragma unroll
        for (int dj = 0; dj < 3; dj++) {
            bool ok = ((unsigned)(kh + di - 1) < 16u) &&
                      ((unsigned)(kw + dj - 1) < 16u);
            if (!ok) acc[di * 3 + dj] = 0.f;
        }
    }

    #pragma unroll
    for (int k = 0; k < 9; k++) {
        float v = acc[k];
        #pragma unroll
        for (int off = 32; off > 0; off >>= 1)
            v += __shfl_xor(v, off, 64);
        acc[k] = v;
    }
    int wid  = tid >> 6;
    int lane = tid & 63;
    if (lane == 0) {
        #pragma unroll
        for (int k = 0; k < 9; k++) red[k][wid] = acc[k];
    }
    __syncthreads();
    if (tid < 9) {
        float s = red[tid][0] + red[tid][1] + red[tid][2] + red[tid][3];
        s += conv_b[oc];
        float g = 0.5f * s * (1.0f + erff(s * 0.70710678118654752f));
        g_out[(b * 16 + oc) * 9 + tid] = g;
    }
}

// ---------------------------------------------------------------------------
// Stage 2: kv[b,k] = sum_j g[b,j] * lin_w[k,j] + lin_b[k]
// ---------------------------------------------------------------------------
__global__ __launch_bounds__(256) void kv_kernel(
    const float* __restrict__ g_in,
    const float* __restrict__ lin_w,
    const float* __restrict__ lin_b,
    float* __restrict__ kv_out)
{
    __shared__ float wsh[25 * 144];
    __shared__ float gsh[144];
    int b   = blockIdx.x;
    int tid = threadIdx.x;

    for (int i = tid; i < 25 * 144; i += 256) wsh[i] = lin_w[i];
    if (tid < 144) gsh[tid] = g_in[b * 144 + tid];
    __syncthreads();

    if (tid < 25) {
        float acc = lin_b[tid];
        #pragma unroll 8
        for (int j = 0; j < 144; j++) acc += gsh[j] * wsh[tid * 144 + j];
        kv_out[b * 25 + tid] = acc;
    }
}

// ---------------------------------------------------------------------------
// Stage 3: depthwise 5x5 conv, reflect pad=2.
// Interior tiles (36/64): NO LDS, NO barrier — each thread reads its 8 input
// rows straight from global (float2+float4+float2 per row, all aligned);
// L1/L2 serve the 5x vertical reuse; 24 independent loads/thread hide latency.
// Edge tiles (28/64): LDS halo-tile path with reflect mapping.
// ---------------------------------------------------------------------------
#define TS   64          // output tile
#define ITS  68          // input tile (halo 2 each side)

__device__ __forceinline__ int reflect_idx(int v, int n) {
    v = (v < 0) ? -v : v;
    v = (v >= n) ? (2 * n - 2 - v) : v;
    return v;
}

__global__ __launch_bounds__(256) void depthwise_kernel(
    const float* __restrict__ img,
    const float* __restrict__ kv,
    float* __restrict__ out)
{
    __shared__ float tile_s[ITS * ITS];

    int bc   = blockIdx.y;          // 0..47  (b*3 + c)
    int b    = bc / C_;
    int tile = blockIdx.x;          // 0..63  (8x8 tiles)
    int tyi  = tile >> 3;
    int txi  = tile & 7;
    int ty0  = tyi * TS;
    int tx0  = txi * TS;

    int tid = threadIdx.x;

    // block-uniform kernel weights -> scalar regs
    float w[25];
    {
        const float* kvp = kv + b * 25;
        #pragma unroll
        for (int i = 0; i < 25; i++) w[i] = kvp[i];
    }

    const float* ip = img + (size_t)bc * H_ * W_;
    float* op       = out + (size_t)bc * H_ * W_;

    int tx = (tid & 15) * 4;   // 0..60
    int ty = (tid >> 4) * 4;   // 0..60

    float acc[4][4];
    #pragma unroll
    for (int i = 0; i < 4; i++)
        #pragma unroll
        for (int j = 0; j < 4; j++) acc[i][j] = 0.f;

    bool interior = (tyi >= 1) && (tyi <= 6) && (txi >= 1) && (txi <= 6);

    if (interior) {
        // ---------- direct-global path: no LDS, no barrier ----------
        const float* base = ip + (size_t)(ty0 + ty - 2) * W_ + (tx0 + tx);
        #pragma unroll
        for (int r = 0; r < 8; r++) {
            const float* rp = base + r * W_;
            float2 a = *(const float2*)(rp - 2);
            float4 m = *(const float4*)(rp);
            float2 c = *(const float2*)(rp + 4);
            float x[8] = {a.x, a.y, m.x, m.y, m.z, m.w, c.x, c.y};
            #pragma unroll
            for (int orow = 0; orow < 4; orow++) {
                int dy = r - orow;
                if (dy >= 0 && dy < 5) {
                    #pragma unroll
                    for (int dx = 0; dx < 5; dx++) {
                        float wv = w[dy * 5 + dx];
                        #pragma unroll
                        for (int oc = 0; oc < 4; oc++)
                            acc[orow][oc] += wv * x[oc + dx];
                    }
                }
            }
        }
    } else {
        // ---------- LDS halo path (reflect at edges) ----------
        bool xedge = (txi == 0) || (txi == 7);
        for (int i = tid; i < ITS * 34; i += 256) {
            int ly = i / 34;
            int c  = i - ly * 34;
            int gy = reflect_idx(ty0 + ly - 2, H_);
            int gx = tx0 + 2 * c - 2;
            const float* rowp = ip + gy * W_;
            float2 v;
            if (!xedge || (unsigned)gx < (unsigned)(W_ - 1)) {
                v = *(const float2*)&rowp[gx];
            } else {
                v.x = rowp[reflect_idx(gx, W_)];
                v.y = rowp[reflect_idx(gx + 1, W_)];
            }
            *(float2*)&tile_s[ly * ITS + 2 * c] = v;
        }
        __syncthreads();

        #pragma unroll
        for (int r = 0; r < 8; r++) {
            const float* rowp = &tile_s[(ty + r) * ITS + tx];
            float4 a = *(const float4*)rowp;
            float4 bb = *(const float4*)(rowp + 4);
            float x[8] = {a.x, a.y, a.z, a.w, bb.x, bb.y, bb.z, bb.w};
            #pragma unroll
            for (int orow = 0; orow < 4; orow++) {
                int dy = r - orow;
                if (dy >= 0 && dy < 5) {
                    #pragma unroll
                    for (int dx = 0; dx < 5; dx++) {
                        float wv = w[dy * 5 + dx];
                        #pragma unroll
                        for (int oc = 0; oc < 4; oc++)
                            acc[orow][oc] += wv * x[oc + dx];
                    }
                }
            }
        }
    }

    #pragma unroll
    for (int orow = 0; orow < 4; orow++) {
        float4 o;
        o.x = acc[orow][0]; o.y = acc[orow][1];
        o.z = acc[orow][2]; o.w = acc[orow][3];
        *(float4*)&op[(ty0 + ty + orow) * W_ + tx0 + tx] = o;
    }
}

extern "C" void kernel_launch(void* const* d_in, const int* in_sizes, int n_in,
                              void* d_out, int out_size, void* d_ws, size_t ws_size,
                              hipStream_t stream) {
    const float* feature = (const float*)d_in[0];
    const float* img     = (const float*)d_in[1];
    const float* conv_w  = (const float*)d_in[2];
    const float* conv_b  = (const float*)d_in[3];
    const float* lin_w   = (const float*)d_in[4];
    const float* lin_b   = (const float*)d_in[5];
    float* out = (float*)d_out;

    float* g_ws  = (float*)d_ws;            // 16*144 floats (post-gelu)
    float* kv_ws = g_ws + 2304;             // 16*25 floats

    patch_conv_kernel<<<B_ * 16, 256, 0, stream>>>(feature, conv_w, conv_b, g_ws);
    kv_kernel<<<B_, 256, 0, stream>>>(g_ws, lin_w, lin_b, kv_ws);

    dim3 grid(64, B_ * C_);
    depthwise_kernel<<<grid, 256, 0, stream>>>(img, kv_ws, out);
}

// Round 5
// 132.663 us; speedup vs baseline: 1.5821x; 1.0297x over previous
//
#include <hip/hip_runtime.h>
#include <math.h>

// Problem shapes
// feature: (16, 32, 64, 64) f32
// img:     (16, 3, 512, 512) f32
// conv_w:  (16, 32, 16, 16) f32   (OIHW)
// conv_b:  (16,)
// lin_w:   (25, 144)
// lin_b:   (25,)
// out:     (16, 3, 512, 512) f32

#define B_  16
#define C_  3
#define H_  512
#define W_  512

// ---------------------------------------------------------------------------
// Stage 1: 16x16 conv (pad=1) on the 16x16 feature patch + bias + exact gelu.
// One block per (b, oc); thread <-> spatial tap for all 32 input channels.
// ---------------------------------------------------------------------------
__global__ __launch_bounds__(256) void patch_conv_kernel(
    const float* __restrict__ feature,
    const float* __restrict__ conv_w,
    const float* __restrict__ conv_b,
    float* __restrict__ g_out)
{
    __shared__ float patch_raw[17 + 8192 + 17]; // guard pads for +-17 offsets
    __shared__ float red[9][4];
    float* patch = patch_raw + 17;

    int blk = blockIdx.x;
    int b   = blk >> 4;
    int oc  = blk & 15;
    int tid = threadIdx.x;

    const float* fb = feature + (size_t)b * 32 * 4096;
    const float* wb = conv_w + (size_t)oc * 8192;

    if (tid < 17) { patch_raw[tid] = 0.f; patch_raw[17 + 8192 + tid] = 0.f; }

    for (int i = tid; i < 8192; i += 256) {
        int ic = i >> 8;
        int r  = i & 255;
        patch[i] = fb[ic * 4096 + (r >> 4) * 64 + (r & 15)];
    }

    float wreg[32];
    #pragma unroll
    for (int ic = 0; ic < 32; ic++) wreg[ic] = wb[ic * 256 + tid];

    __syncthreads();

    int kh = tid >> 4;
    int kw = tid & 15;

    float acc[9];
    #pragma unroll
    for (int k = 0; k < 9; k++) acc[k] = 0.f;

    #pragma unroll 4
    for (int ic = 0; ic < 32; ic++) {
        int base = ic * 256 + tid;
        float wv = wreg[ic];
        #pragma unroll
        for (int di = 0; di < 3; di++) {
            #pragma unroll
            for (int dj = 0; dj < 3; dj++) {
                acc[di * 3 + dj] += patch[base + (di - 1) * 16 + (dj - 1)] * wv;
            }
        }
    }

    #pragma unroll
    for (int di = 0; di < 3; di++) {
        #pragma unroll
        for (int dj = 0; dj < 3; dj++) {
            bool ok = ((unsigned)(kh + di - 1) < 16u) &&
                      ((unsigned)(kw + dj - 1) < 16u);
            if (!ok) acc[di * 3 + dj] = 0.f;
        }
    }

    #pragma unroll
    for (int k = 0; k < 9; k++) {
        float v = acc[k];
        #pragma unroll
        for (int off = 32; off > 0; off >>= 1)
            v += __shfl_xor(v, off, 64);
        acc[k] = v;
    }
    int wid  = tid >> 6;
    int lane = tid & 63;
    if (lane == 0) {
        #pragma unroll
        for (int k = 0; k < 9; k++) red[k][wid] = acc[k];
    }
    __syncthreads();
    if (tid < 9) {
        float s = red[tid][0] + red[tid][1] + red[tid][2] + red[tid][3];
        s += conv_b[oc];
        float g = 0.5f * s * (1.0f + erff(s * 0.70710678118654752f));
        g_out[(b * 16 + oc) * 9 + tid] = g;
    }
}

// ---------------------------------------------------------------------------
// Stage 2: kv[b,k] = sum_j g[b,j] * lin_w[k,j] + lin_b[k]
// ---------------------------------------------------------------------------
__global__ __launch_bounds__(256) void kv_kernel(
    const float* __restrict__ g_in,
    const float* __restrict__ lin_w,
    const float* __restrict__ lin_b,
    float* __restrict__ kv_out)
{
    __shared__ float wsh[25 * 144];
    __shared__ float gsh[144];
    int b   = blockIdx.x;
    int tid = threadIdx.x;

    for (int i = tid; i < 25 * 144; i += 256) wsh[i] = lin_w[i];
    if (tid < 144) gsh[tid] = g_in[b * 144 + tid];
    __syncthreads();

    if (tid < 25) {
        float acc = lin_b[tid];
        #pragma unroll 8
        for (int j = 0; j < 144; j++) acc += gsh[j] * wsh[tid * 144 + j];
        kv_out[b * 25 + tid] = acc;
    }
}

// ---------------------------------------------------------------------------
// Stage 3: depthwise 5x5 conv, reflect pad=2. NO LDS, NO barriers.
// Block tile 64 wide x 128 tall; 256 threads, each 4 wide x 8 tall.
// Each thread streams its 12 input rows through a 4-deep register window
// (12 loads in flight) -> enough outstanding VMEM to run at HBM rate.
// y-reflect: branchless per-row pointer remap. x-reflect (txi 0/7): uniform
// per-block scalar-load path, no divergence inside a wave.
// ---------------------------------------------------------------------------
#define TSX  64          // tile width
#define TSY  128         // tile height

__device__ __forceinline__ int reflect_idx(int v, int n) {
    v = (v < 0) ? -v : v;
    v = (v >= n) ? (2 * n - 2 - v) : v;
    return v;
}

template <bool XFAST>
__device__ __forceinline__ void dw_tile(
    const float* __restrict__ ip, float* __restrict__ op,
    const float* w, int ty0, int tx0, int tx, int tyl)
{
    int gx0 = tx0 + tx;            // x of this thread's first output column
    int xid[8];
    if (!XFAST) {
        #pragma unroll
        for (int j = 0; j < 8; j++) xid[j] = reflect_idx(gx0 - 2 + j, W_);
    }

    float acc[8][4];
    #pragma unroll
    for (int i = 0; i < 8; i++)
        #pragma unroll
        for (int j = 0; j < 4; j++) acc[i][j] = 0.f;

    float win[4][8];

    // prefetch rows 0..3
    #pragma unroll
    for (int r = 0; r < 4; r++) {
        int gy = reflect_idx(ty0 + tyl + r - 2, H_);
        const float* rowp = ip + (size_t)gy * W_;
        if (XFAST) {
            const float* rp = rowp + gx0;
            float2 a = *(const float2*)(rp - 2);
            float4 m = *(const float4*)(rp);
            float2 c = *(const float2*)(rp + 4);
            win[r][0] = a.x; win[r][1] = a.y;
            win[r][2] = m.x; win[r][3] = m.y; win[r][4] = m.z; win[r][5] = m.w;
            win[r][6] = c.x; win[r][7] = c.y;
        } else {
            #pragma unroll
            for (int j = 0; j < 8; j++) win[r][j] = rowp[xid[j]];
        }
    }

    // stream 12 rows; consume row r, prefetch row r+4 into the freed slot
    #pragma unroll
    for (int r = 0; r < 12; r++) {
        const float* x = win[r & 3];
        #pragma unroll
        for (int orow = 0; orow < 8; orow++) {
            int dy = r - orow;
            if (dy >= 0 && dy < 5) {            // compile-time after unroll
                #pragma unroll
                for (int dx = 0; dx < 5; dx++) {
                    float wv = w[dy * 5 + dx];
                    #pragma unroll
                    for (int oc = 0; oc < 4; oc++)
                        acc[orow][oc] += wv * x[oc + dx];
                }
            }
        }
        if (r + 4 < 12) {
            int rn = r + 4;
            int gy = reflect_idx(ty0 + tyl + rn - 2, H_);
            const float* rowp = ip + (size_t)gy * W_;
            float* wdst = win[r & 3];
            if (XFAST) {
                const float* rp = rowp + gx0;
                float2 a = *(const float2*)(rp - 2);
                float4 m = *(const float4*)(rp);
                float2 c = *(const float2*)(rp + 4);
                wdst[0] = a.x; wdst[1] = a.y;
                wdst[2] = m.x; wdst[3] = m.y; wdst[4] = m.z; wdst[5] = m.w;
                wdst[6] = c.x; wdst[7] = c.y;
            } else {
                #pragma unroll
                for (int j = 0; j < 8; j++) wdst[j] = rowp[xid[j]];
            }
        }
    }

    #pragma unroll
    for (int orow = 0; orow < 8; orow++) {
        float4 o;
        o.x = acc[orow][0]; o.y = acc[orow][1];
        o.z = acc[orow][2]; o.w = acc[orow][3];
        *(float4*)&op[(size_t)(ty0 + tyl + orow) * W_ + gx0] = o;
    }
}

__global__ __launch_bounds__(256) void depthwise_kernel(
    const float* __restrict__ img,
    const float* __restrict__ kv,
    float* __restrict__ out)
{
    int bc   = blockIdx.y;          // 0..47  (b*3 + c)
    int b    = bc / C_;
    int tile = blockIdx.x;          // 0..31  (8 x-tiles, 4 y-tiles)
    int tyi  = tile >> 3;
    int txi  = tile & 7;
    int ty0  = tyi * TSY;
    int tx0  = txi * TSX;

    int tid = threadIdx.x;
    int tx  = (tid & 15) * 4;       // 0..60
    int tyl = (tid >> 4) * 8;       // 0..120

    // block-uniform kernel weights, forced to SGPRs
    float w[25];
    {
        const float* kvp = kv + b * 25;
        #pragma unroll
        for (int i = 0; i < 25; i++)
            w[i] = __int_as_float(
                __builtin_amdgcn_readfirstlane(__float_as_int(kvp[i])));
    }

    const float* ip = img + (size_t)bc * H_ * W_;
    float* op       = out + (size_t)bc * H_ * W_;

    if (txi >= 1 && txi <= 6)
        dw_tile<true >(ip, op, w, ty0, tx0, tx, tyl);
    else
        dw_tile<false>(ip, op, w, ty0, tx0, tx, tyl);
}

extern "C" void kernel_launch(void* const* d_in, const int* in_sizes, int n_in,
                              void* d_out, int out_size, void* d_ws, size_t ws_size,
                              hipStream_t stream) {
    const float* feature = (const float*)d_in[0];
    const float* img     = (const float*)d_in[1];
    const float* conv_w  = (const float*)d_in[2];
    const float* conv_b  = (const float*)d_in[3];
    const float* lin_w   = (const float*)d_in[4];
    const float* lin_b   = (const float*)d_in[5];
    float* out = (float*)d_out;

    float* g_ws  = (float*)d_ws;            // 16*144 floats (post-gelu)
    float* kv_ws = g_ws + 2304;             // 16*25 floats

    patch_conv_kernel<<<B_ * 16, 256, 0, stream>>>(feature, conv_w, conv_b, g_ws);
    kv_kernel<<<B_, 256, 0, stream>>>(g_ws, lin_w, lin_b, kv_ws);

    dim3 grid(32, B_ * C_);
    depthwise_kernel<<<grid, 256, 0, stream>>>(img, kv_ws, out);
}